// Round 1
// baseline (1156.516 us; speedup 1.0000x reference)
//
#include <hip/hip_runtime.h>
#include <hip/hip_fp16.h>

typedef _Float16 f16;
typedef _Float16 f16x8 __attribute__((ext_vector_type(8)));
typedef _Float16 f16x4 __attribute__((ext_vector_type(4)));
typedef float f32x4 __attribute__((ext_vector_type(4)));

#define L2E 1.4426950408889634f

// workspace layout (bytes)
#define WQ_OFF   0         // 768*256 f16   qkv weight, row-major [n][k]
#define PW_OFF   393216    // 256*256 f16   proj weight, row-major [n][k]
#define QB_OFF   524288    // 768 f32       concat qkv bias (k-bias = 0)
#define SC_OFF   527360    // 8 f32         exp(min(logit_scale, ln100))
#define TBL_OFF  527616    // 225*8 f32     cpb mlp table
#define BB_OFF   535040    // 8*64*64 f32   folded bias: (16*sigmoid - sc - 16) * log2e

// ---------------- prep kernels ----------------

__global__ void prep0(const float* __restrict__ qw, const float* __restrict__ prw,
                      const float* __restrict__ qbias, const float* __restrict__ vbias,
                      const float* __restrict__ ls, char* __restrict__ ws) {
    int t = blockIdx.x * 256 + threadIdx.x;
    f16* wq = (f16*)(ws + WQ_OFF);
    f16* pw = (f16*)(ws + PW_OFF);
    if (t < 196608) wq[t] = (f16)qw[t];
    else            pw[t - 196608] = (f16)prw[t - 196608];
    if (t < 768) {
        float b = t < 256 ? qbias[t] : (t < 512 ? 0.f : vbias[t - 512]);
        ((float*)(ws + QB_OFF))[t] = b;
    }
    if (t < 8) ((float*)(ws + SC_OFF))[t] = expf(fminf(ls[t], 4.6051701859880914f));
}

__device__ __forceinline__ float norm_coord(int u) { // u in 0..14
    float v = (float)(u - 7) * (8.0f / 7.0f);
    float s = (v > 0.f) ? 1.f : ((v < 0.f) ? -1.f : 0.f);
    return s * log2f(fabsf(v) + 1.f) * (1.f / 3.f);
}

__global__ void prep1(const float* __restrict__ w1, const float* __restrict__ b1,
                      const float* __restrict__ w2, char* __restrict__ ws) {
    int t = blockIdx.x * 256 + threadIdx.x; // 1800 used
    if (t >= 1800) return;
    int p = t >> 3, h = t & 7;
    float ta = norm_coord(p / 15);
    float tb = norm_coord(p % 15);
    float acc = 0.f;
    for (int j = 0; j < 512; ++j) {
        float hv = fmaf(w1[2 * j], ta, fmaf(w1[2 * j + 1], tb, b1[j]));
        acc = fmaf(fmaxf(hv, 0.f), w2[h * 512 + j], acc);
    }
    ((float*)(ws + TBL_OFF))[p * 8 + h] = acc;
}

__global__ void prep2(char* __restrict__ ws) {
    int t = blockIdx.x * 256 + threadIdx.x; // 32768 = 8*64*64
    int h = t >> 12, i = (t >> 6) & 63, j = t & 63;
    int ri = ((i >> 3) - (j >> 3) + 7) * 15 + ((i & 7) - (j & 7) + 7);
    float bv = ((const float*)(ws + TBL_OFF))[ri * 8 + h];
    float sg = 1.f / (1.f + expf(-bv));
    float sch = ((const float*)(ws + SC_OFF))[h];
    ((float*)(ws + BB_OFF))[t] = (16.f * sg - sch - 16.f) * L2E;
}

// ---------------- fused main kernel ----------------
// 1 block = 1 window. 512 threads = 8 waves; wave w owns 96 qkv cols then head w.
// LDS map:
//   R1 [0,32768)      : xs [64][256] f16 (swz)  -> later O [64][256] f16 (swz)
//   R2 [32768,98304)  : qks [64][512] f16 (swz) -> later P[w] = 8 x [64][64] f16 (swz)
//   R3 [98304,131072) : vts [8][32][64] f16 (swz)  (v stored transposed per head)
//   [131072,135168)   : rqk [2][8][64] f32  (rq' = sc*log2e/|q|, rk = 1/|k|)
#define SWZ(row) (((row) & 7) << 4)

__global__ __launch_bounds__(512, 2)
void swin_fused(const float* __restrict__ x, const f16* __restrict__ wq,
                const f16* __restrict__ pw, const float* __restrict__ qb,
                const float* __restrict__ sc, const float* __restrict__ biasB,
                const float* __restrict__ pb, float* __restrict__ out) {
    extern __shared__ char lds[];
    const int tid = threadIdx.x;
    const int lane = tid & 63;
    const int w = tid >> 6;
    const int g = lane >> 4;
    const int c = lane & 15;
    const int win = blockIdx.x;
    const float* xw = x + (size_t)win * 16384;

    // ---- phase 0: stage x -> LDS fp16 (swizzled) ----
    #pragma unroll
    for (int it = 0; it < 8; ++it) {
        int e4 = tid + it * 512;                 // float4 index 0..4095
        float4 v = ((const float4*)xw)[e4];
        int eidx = e4 * 4;
        int row = eidx >> 8, col = eidx & 255;
        f16x4 h4 = {(f16)v.x, (f16)v.y, (f16)v.z, (f16)v.w};
        int off = (row << 9) + (col << 1);
        off ^= SWZ(row);
        *(f16x4*)(lds + off) = h4;
    }
    __syncthreads(); // (1)

    // ---- phase 1: qkv GEMM. wave w -> cols [96w, 96w+96), 3 pairs of 16-col tiles ----
    #pragma unroll
    for (int p = 0; p < 3; ++p) {
        int n0 = w * 96 + p * 32;
        f32x4 acc[2][4] = {};
        for (int kk = 0; kk < 8; ++kk) {
            int kb = kk * 32 + g * 8;
            f16x8 a[4];
            #pragma unroll
            for (int mi = 0; mi < 4; ++mi) {
                int row = mi * 16 + c;
                int off = (row << 9) + (kb << 1);
                off ^= SWZ(row);
                a[mi] = *(const f16x8*)(lds + off);
            }
            #pragma unroll
            for (int t = 0; t < 2; ++t) {
                int n = n0 + t * 16 + c;
                f16x8 b = *(const f16x8*)(wq + n * 256 + kb);
                #pragma unroll
                for (int mi = 0; mi < 4; ++mi)
                    acc[t][mi] = __builtin_amdgcn_mfma_f32_16x16x32_f16(a[mi], b, acc[t][mi], 0, 0, 0);
            }
        }
        #pragma unroll
        for (int t = 0; t < 2; ++t) {
            int nt0 = n0 + t * 16;
            int col = nt0 + c;
            float bias = qb[col];
            if (nt0 < 512) { // q or k -> qks [64][512]
                #pragma unroll
                for (int mi = 0; mi < 4; ++mi)
                    #pragma unroll
                    for (int r = 0; r < 4; ++r) {
                        int row = mi * 16 + g * 4 + r;
                        int off = 32768 + (row << 10) + (col << 1);
                        off ^= SWZ(row);
                        *(f16*)(lds + off) = (f16)(acc[t][mi][r] + bias);
                    }
            } else {         // v -> vts [h][32][64] transposed
                int h = (col - 512) >> 5, d = (col - 512) & 31;
                #pragma unroll
                for (int mi = 0; mi < 4; ++mi)
                    #pragma unroll
                    for (int r = 0; r < 4; ++r) {
                        int row = mi * 16 + g * 4 + r;
                        int off = 98304 + (h << 12) + (d << 7) + (row << 1);
                        off ^= SWZ(d);
                        *(f16*)(lds + off) = (f16)(acc[t][mi][r] + bias);
                    }
            }
        }
    }
    __syncthreads(); // (2)

    // ---- phase 2: q/k inverse norms for head w (lane = token) ----
    {
        float ssq = 0.f, ssk = 0.f;
        int row = lane;
        #pragma unroll
        for (int d4 = 0; d4 < 4; ++d4) {
            int offq = 32768 + (row << 10) + ((w * 32 + d4 * 8) << 1);
            offq ^= SWZ(row);
            f16x8 qv = *(const f16x8*)(lds + offq);
            int offk = 32768 + (row << 10) + ((256 + w * 32 + d4 * 8) << 1);
            offk ^= SWZ(row);
            f16x8 kv = *(const f16x8*)(lds + offk);
            #pragma unroll
            for (int j = 0; j < 8; ++j) {
                float q = (float)qv[j]; ssq = fmaf(q, q, ssq);
                float k = (float)kv[j]; ssk = fmaf(k, k, ssk);
            }
        }
        float* rqk = (float*)(lds + 131072);
        rqk[w * 64 + row]       = sc[w] * L2E * __builtin_amdgcn_rsqf(fmaxf(ssq, 1e-24f));
        rqk[512 + w * 64 + row] = __builtin_amdgcn_rsqf(fmaxf(ssk, 1e-24f));
    }

    // ---- phase 3: QK^T for head w ----
    f32x4 s[4][4];
    {
        f16x8 afr[4], bfr[4];
        #pragma unroll
        for (int mi = 0; mi < 4; ++mi) {
            int row = mi * 16 + c;
            int off = 32768 + (row << 10) + ((w * 32 + g * 8) << 1);
            off ^= SWZ(row);
            afr[mi] = *(const f16x8*)(lds + off);
        }
        #pragma unroll
        for (int nj = 0; nj < 4; ++nj) {
            int row = nj * 16 + c;
            int off = 32768 + (row << 10) + ((256 + w * 32 + g * 8) << 1);
            off ^= SWZ(row);
            bfr[nj] = *(const f16x8*)(lds + off);
        }
        f32x4 zero = {};
        #pragma unroll
        for (int mi = 0; mi < 4; ++mi)
            #pragma unroll
            for (int nj = 0; nj < 4; ++nj)
                s[mi][nj] = __builtin_amdgcn_mfma_f32_16x16x32_f16(afr[mi], bfr[nj], zero, 0, 0, 0);
    }

    // ---- phase 4: softmax (max replaced by static bound, folded into biasB) ----
    float psum[4][4];
    {
        const float* rqk = (const float*)(lds + 131072);
        const float* bb = biasB + (w << 12);
        f32x4 rq4[4];
        #pragma unroll
        for (int mi = 0; mi < 4; ++mi)
            rq4[mi] = *(const f32x4*)(rqk + w * 64 + mi * 16 + g * 4);
        float rk[4];
        #pragma unroll
        for (int nj = 0; nj < 4; ++nj)
            rk[nj] = rqk[512 + w * 64 + nj * 16 + c];
        #pragma unroll
        for (int mi = 0; mi < 4; ++mi) {
            #pragma unroll
            for (int r = 0; r < 4; ++r) {
                int i = mi * 16 + g * 4 + r;
                float rs = rq4[mi][r];
                float t0 = exp2f(fmaf(s[mi][0][r] * rs, rk[0], bb[i * 64 + c]));
                float t1 = exp2f(fmaf(s[mi][1][r] * rs, rk[1], bb[i * 64 + 16 + c]));
                float t2 = exp2f(fmaf(s[mi][2][r] * rs, rk[2], bb[i * 64 + 32 + c]));
                float t3 = exp2f(fmaf(s[mi][3][r] * rs, rk[3], bb[i * 64 + 48 + c]));
                s[mi][0][r] = t0; s[mi][1][r] = t1; s[mi][2][r] = t2; s[mi][3][r] = t3;
                float t = t0 + t1 + t2 + t3;
                t += __shfl_xor(t, 1);
                t += __shfl_xor(t, 2);
                t += __shfl_xor(t, 4);
                t += __shfl_xor(t, 8);
                psum[mi][r] = __builtin_amdgcn_rcpf(t);
            }
        }
    }
    __syncthreads(); // (3) all QK reads of qks done -> P may overwrite
    {
        char* P = lds + 32768 + (w << 13);
        #pragma unroll
        for (int mi = 0; mi < 4; ++mi)
            #pragma unroll
            for (int nj = 0; nj < 4; ++nj)
                #pragma unroll
                for (int r = 0; r < 4; ++r) {
                    int row = mi * 16 + g * 4 + r;
                    int off = (row << 7) + ((nj * 16 + c) << 1);
                    off ^= SWZ(row);
                    *(f16*)(P + off) = (f16)(s[mi][nj][r] * psum[mi][r]);
                }
    }

    // ---- phase 5: PV for head w, write O into R1 ----
    {
        const char* P = lds + 32768 + (w << 13);
        const char* V = lds + 98304 + (w << 12);
        f32x4 oa[4][2] = {};
        #pragma unroll
        for (int kk = 0; kk < 2; ++kk) {
            int tb = kk * 32 + g * 8;
            f16x8 vf[2];
            #pragma unroll
            for (int ni = 0; ni < 2; ++ni) {
                int n = ni * 16 + c;
                int off = (n << 7) + (tb << 1);
                off ^= SWZ(n);
                vf[ni] = *(const f16x8*)(V + off);
            }
            #pragma unroll
            for (int mi = 0; mi < 4; ++mi) {
                int row = mi * 16 + c;
                int off = (row << 7) + (tb << 1);
                off ^= SWZ(row);
                f16x8 pf = *(const f16x8*)(P + off);
                #pragma unroll
                for (int ni = 0; ni < 2; ++ni)
                    oa[mi][ni] = __builtin_amdgcn_mfma_f32_16x16x32_f16(pf, vf[ni], oa[mi][ni], 0, 0, 0);
            }
        }
        #pragma unroll
        for (int mi = 0; mi < 4; ++mi)
            #pragma unroll
            for (int ni = 0; ni < 2; ++ni)
                #pragma unroll
                for (int r = 0; r < 4; ++r) {
                    int row = mi * 16 + g * 4 + r;
                    int col = (w << 5) + ni * 16 + c;
                    int off = (row << 9) + (col << 1);
                    off ^= SWZ(row);
                    *(f16*)(lds + off) = (f16)oa[mi][ni][r];
                }
    }
    __syncthreads(); // (4)

    // ---- phase 6: proj GEMM. wave w -> out cols [32w, 32w+32) ----
    #pragma unroll
    for (int nt = 0; nt < 2; ++nt) {
        int n0 = (w << 5) + nt * 16;
        f32x4 acc[4] = {};
        for (int kk = 0; kk < 8; ++kk) {
            int kb = kk * 32 + g * 8;
            f16x8 b = *(const f16x8*)(pw + (n0 + c) * 256 + kb);
            #pragma unroll
            for (int mi = 0; mi < 4; ++mi) {
                int row = mi * 16 + c;
                int off = (row << 9) + (kb << 1);
                off ^= SWZ(row);
                f16x8 a = *(const f16x8*)(lds + off);
                acc[mi] = __builtin_amdgcn_mfma_f32_16x16x32_f16(a, b, acc[mi], 0, 0, 0);
            }
        }
        float pbias = pb[n0 + c];
        #pragma unroll
        for (int mi = 0; mi < 4; ++mi)
            #pragma unroll
            for (int r = 0; r < 4; ++r) {
                int row = mi * 16 + g * 4 + r;
                out[(size_t)win * 16384 + row * 256 + n0 + c] = acc[mi][r] + pbias;
            }
    }
}

// ---------------- launch ----------------

extern "C" void kernel_launch(void* const* d_in, const int* in_sizes, int n_in,
                              void* d_out, int out_size, void* d_ws, size_t ws_size,
                              hipStream_t stream) {
    (void)in_sizes; (void)n_in; (void)out_size; (void)ws_size;
    const float* x   = (const float*)d_in[0];
    const float* qw  = (const float*)d_in[1];
    const float* qb_ = (const float*)d_in[2];
    const float* vb_ = (const float*)d_in[3];
    const float* ls  = (const float*)d_in[4];
    const float* w1  = (const float*)d_in[5];
    const float* b1  = (const float*)d_in[6];
    const float* w2  = (const float*)d_in[7];
    const float* prw = (const float*)d_in[8];
    const float* pb  = (const float*)d_in[9];
    float* out = (float*)d_out;
    char* ws = (char*)d_ws;

    prep0<<<1024, 256, 0, stream>>>(qw, prw, qb_, vb_, ls, ws);
    prep1<<<8, 256, 0, stream>>>(w1, b1, w2, ws);
    prep2<<<128, 256, 0, stream>>>(ws);

    (void)hipFuncSetAttribute((const void*)swin_fused,
                              hipFuncAttributeMaxDynamicSharedMemorySize, 135168);
    swin_fused<<<8192, 512, 135168, stream>>>(
        x,
        (const f16*)(ws + WQ_OFF), (const f16*)(ws + PW_OFF),
        (const float*)(ws + QB_OFF), (const float*)(ws + SC_OFF),
        (const float*)(ws + BB_OFF), pb, out);
}